// Round 4
// baseline (15507.535 us; speedup 1.0000x reference)
//
#include <hip/hip_runtime.h>
#include <cstdint>
#include <cstddef>

#define V_   4096
#define D_   1024
#define H_   16
#define NL_  12
#define DFF_ 2752
#define DH_  64
#define T_   1365
#define B_   2
#define BT_  (B_ * T_)

typedef __attribute__((ext_vector_type(8))) short short8_t;  // 8 bf16 (4 VGPRs)
typedef __attribute__((ext_vector_type(4))) float f32x4;

static __device__ __forceinline__ int scale_of(int t) {
  return (t < 1) ? 0 : (t < 5) ? 1 : (t < 21) ? 2 : (t < 85) ? 3 : (t < 341) ? 4 : 5;
}
static __device__ __forceinline__ int scale_start(int s) {
  return (s == 0) ? 0 : (s == 1) ? 1 : (s == 2) ? 5 : (s == 3) ? 21 : (s == 4) ? 85 : 341;
}
static __device__ __forceinline__ int scale_end(int s) {
  return (s == 0) ? 1 : (s == 1) ? 5 : (s == 2) ? 21 : (s == 3) ? 85 : (s == 4) ? 341 : 1365;
}

// split fp32 x ≈ hi + lo (both bf16, RNE). Dropped lo*lo in products ≈ 2^-18 rel.
static __device__ __forceinline__ void cvt_hl(float x, unsigned short& h, unsigned short& l) {
  uint32_t b = __builtin_bit_cast(uint32_t, x);
  uint32_t hb = b + 0x7FFFu + ((b >> 16) & 1u);
  h = (unsigned short)(hb >> 16);
  float hf = __builtin_bit_cast(float, hb & 0xFFFF0000u);
  float r = x - hf;
  uint32_t rb = __builtin_bit_cast(uint32_t, r);
  rb += 0x7FFFu + ((rb >> 16) & 1u);
  l = (unsigned short)(rb >> 16);
}

static __device__ __forceinline__ void cvt8(const float* vv, short8_t& h8, short8_t& l8) {
#pragma unroll
  for (int j = 0; j < 8; ++j) {
    unsigned short h, l;
    cvt_hl(vv[j], h, l);
    h8[j] = (short)h;
    l8[j] = (short)l;
  }
}

// raw barriers: do NOT drain vmcnt (keeps prefetch loads in flight across barriers)
static __device__ __forceinline__ void bar_lgkm() {
  asm volatile("s_waitcnt lgkmcnt(0)" ::: "memory");
  __builtin_amdgcn_sched_barrier(0);
  __builtin_amdgcn_s_barrier();
  __builtin_amdgcn_sched_barrier(0);
}
static __device__ __forceinline__ void bar_plain() {
  __builtin_amdgcn_sched_barrier(0);
  __builtin_amdgcn_s_barrier();
  __builtin_amdgcn_sched_barrier(0);
}

// ---------------- embed
__global__ __launch_bounds__(256) void embed_kernel(
    const int* __restrict__ i0, const int* __restrict__ i1, const int* __restrict__ i2,
    const int* __restrict__ i3, const int* __restrict__ i4, const int* __restrict__ i5,
    const float* __restrict__ tok_emb, const float* __restrict__ scl_emb,
    const float* __restrict__ start_tok, float* __restrict__ h, int* __restrict__ tokens) {
  int row = blockIdx.x;              // b*T + t
  int b = row / T_, t = row % T_;
  int s = scale_of(t);
  int st = scale_start(s);
  int sz = scale_end(s) - st;
  const int* ip = (s == 0) ? i0 : (s == 1) ? i1 : (s == 2) ? i2 : (s == 3) ? i3 : (s == 4) ? i4 : i5;
  int tok = ip[b * sz + (t - st)];
  if (threadIdx.x == 0) tokens[row] = tok;
  const float* base = (t == 0) ? start_tok : (tok_emb + (size_t)tok * D_);
  size_t ho = (size_t)row * D_;
  for (int d = threadIdx.x; d < D_; d += 256)
    h[ho + d] = base[d] + scl_emb[s * D_ + d];
}

// ---------------- split-bf16 MFMA GEMM body, software-pipelined.
// NT=0: W is [K,N]; NT=1: W is [N,K]. 128x128 tile, BK=32, 4 waves of 64x64.
// Single LDS buffer, reg-staged prefetch of tile k+1 issued before MFMA of tile k.
struct GemmSmem {
  unsigned short AsH[128][40];
  unsigned short AsL[128][40];
  unsigned short BsH[128][40];
  unsigned short BsL[128][40];
};

template <int NT>
static __device__ __forceinline__ void gemm_body(
    GemmSmem& sm, const float* __restrict__ A, const float* __restrict__ W,
    float* __restrict__ C, int M, int N, int K, int kbase, int klen, int bm, int bn) {
  const int tx = threadIdx.x;
  const int wave = tx >> 6;
  const int lane = tx & 63;
  const int wr = (wave >> 1) * 64;
  const int wc = (wave & 1) * 64;
  const int fr = lane & 15;
  const int kh = lane >> 4;

  float4 pa[4];
  float pb[4][4];

  auto load_tile = [&](int k0) {
#pragma unroll
    for (int it = 0; it < 4; ++it) {
      int slot = it * 256 + tx;
      int m = slot >> 3, kq = slot & 7;
      int gm = bm + m;
      if (gm < M) pa[it] = *(const float4*)(A + (size_t)gm * K + (k0 + 4 * kq));
      else        pa[it] = float4{0.f, 0.f, 0.f, 0.f};
    }
#pragma unroll
    for (int it = 0; it < 4; ++it) {
      int slot = it * 256 + tx;
      if constexpr (NT) {
        int n = slot >> 3, kq = slot & 7;
        int gn = bn + n;
        float4 t = {0.f, 0.f, 0.f, 0.f};
        if (gn < N) t = *(const float4*)(W + (size_t)gn * K + (k0 + 4 * kq));
        pb[it][0] = t.x; pb[it][1] = t.y; pb[it][2] = t.z; pb[it][3] = t.w;
      } else {
        int n = slot & 127, kq = slot >> 7;
        int gn = bn + n;
        if (gn < N) {
#pragma unroll
          for (int r = 0; r < 4; ++r)
            pb[it][r] = W[(size_t)(k0 + 4 * kq + r) * N + gn];
        } else {
          pb[it][0] = pb[it][1] = pb[it][2] = pb[it][3] = 0.f;
        }
      }
    }
  };

  auto store_tile = [&]() {
#pragma unroll
    for (int it = 0; it < 4; ++it) {
      int slot = it * 256 + tx;
      int m = slot >> 3, kq = slot & 7;
      ushort4 hh, ll;
      cvt_hl(pa[it].x, hh.x, ll.x); cvt_hl(pa[it].y, hh.y, ll.y);
      cvt_hl(pa[it].z, hh.z, ll.z); cvt_hl(pa[it].w, hh.w, ll.w);
      *(ushort4*)&sm.AsH[m][4 * kq] = hh;
      *(ushort4*)&sm.AsL[m][4 * kq] = ll;
    }
#pragma unroll
    for (int it = 0; it < 4; ++it) {
      int slot = it * 256 + tx;
      int n, kq;
      if constexpr (NT) { n = slot >> 3; kq = slot & 7; }
      else              { n = slot & 127; kq = slot >> 7; }
      ushort4 hh, ll;
      cvt_hl(pb[it][0], hh.x, ll.x); cvt_hl(pb[it][1], hh.y, ll.y);
      cvt_hl(pb[it][2], hh.z, ll.z); cvt_hl(pb[it][3], hh.w, ll.w);
      *(ushort4*)&sm.BsH[n][4 * kq] = hh;
      *(ushort4*)&sm.BsL[n][4 * kq] = ll;
    }
  };

  f32x4 acc[4][4];
#pragma unroll
  for (int mi = 0; mi < 4; ++mi)
#pragma unroll
    for (int ni = 0; ni < 4; ++ni) acc[mi][ni] = {0.f, 0.f, 0.f, 0.f};

  const int nsteps = klen >> 5;
  load_tile(kbase);
  store_tile();

  for (int st = 0; st < nsteps; ++st) {
    bar_lgkm();   // LDS writes of this tile complete, all waves arrived

    short8_t ah[4], al[4], bh[4], bl[4];
#pragma unroll
    for (int mi = 0; mi < 4; ++mi) {
      int r = wr + mi * 16 + fr;
      ah[mi] = *(const short8_t*)&sm.AsH[r][8 * kh];
      al[mi] = *(const short8_t*)&sm.AsL[r][8 * kh];
    }
#pragma unroll
    for (int ni = 0; ni < 4; ++ni) {
      int c = wc + ni * 16 + fr;
      bh[ni] = *(const short8_t*)&sm.BsH[c][8 * kh];
      bl[ni] = *(const short8_t*)&sm.BsL[c][8 * kh];
    }

    if (st + 1 < nsteps) load_tile(kbase + (st + 1) * 32);  // prefetch: latency hides under MFMA

#pragma unroll
    for (int mi = 0; mi < 4; ++mi)
#pragma unroll
      for (int ni = 0; ni < 4; ++ni) {
        acc[mi][ni] = __builtin_amdgcn_mfma_f32_16x16x32_bf16(ah[mi], bh[ni], acc[mi][ni], 0, 0, 0);
        acc[mi][ni] = __builtin_amdgcn_mfma_f32_16x16x32_bf16(ah[mi], bl[ni], acc[mi][ni], 0, 0, 0);
        acc[mi][ni] = __builtin_amdgcn_mfma_f32_16x16x32_bf16(al[mi], bh[ni], acc[mi][ni], 0, 0, 0);
      }

    bar_plain();  // all waves done reading LDS (implied by their MFMA lgkm waits)
    if (st + 1 < nsteps) store_tile();
  }

  const int rsub = (lane >> 4) * 4;
#pragma unroll
  for (int mi = 0; mi < 4; ++mi) {
#pragma unroll
    for (int j = 0; j < 4; ++j) {
      int gm = bm + wr + mi * 16 + rsub + j;
      if (gm >= M) continue;
      float* crow = C + (size_t)gm * N;
#pragma unroll
      for (int ni = 0; ni < 4; ++ni) {
        int gn = bn + wc + ni * 16 + fr;
        if (gn < N) crow[gn] = acc[mi][ni][j];
      }
    }
  }
}

template <int NT>
__global__ __launch_bounds__(256, 3) void gemm_mfma(
    const float* __restrict__ A, const float* __restrict__ W, float* __restrict__ C,
    int M, int N, int K) {
  __shared__ GemmSmem sm;
  gemm_body<NT>(sm, A, W, C, M, N, K, 0, K, blockIdx.y * 128, blockIdx.x * 128);
}

// split-K: blockIdx.z = chunk; each chunk writes its own partial C
template <int NT>
__global__ __launch_bounds__(256, 3) void gemm_splitk(
    const float* __restrict__ A, const float* __restrict__ W,
    float* __restrict__ C0, float* __restrict__ C1,
    float* __restrict__ C2, float* __restrict__ C3,
    int M, int N, int K, int klen) {
  __shared__ GemmSmem sm;
  int sk = blockIdx.z;
  float* C = (sk == 0) ? C0 : (sk == 1) ? C1 : (sk == 2) ? C2 : C3;
  gemm_body<NT>(sm, A, W, C, M, N, K, sk * klen, klen, blockIdx.y * 128, blockIdx.x * 128);
}

// fused QKV: grid.x = 24 (3 mats x 8 tiles of N=1024)
__global__ __launch_bounds__(256, 3) void gemm_qkv(
    const float* __restrict__ A,
    const float* __restrict__ W0, const float* __restrict__ W1, const float* __restrict__ W2,
    float* __restrict__ C0, float* __restrict__ C1, float* __restrict__ C2, int M, int K) {
  __shared__ GemmSmem sm;
  int mat = blockIdx.x >> 3;
  int bn = (blockIdx.x & 7) * 128;
  const float* W = (mat == 0) ? W0 : (mat == 1) ? W1 : W2;
  float* C = (mat == 0) ? C0 : (mat == 1) ? C1 : C2;
  gemm_body<0>(sm, A, W, C, M, 1024, K, 0, K, blockIdx.y * 128, bn);
}

// fused w1/w3: grid.x = 44 (2 mats x 22 tiles of N=2752)
__global__ __launch_bounds__(256, 3) void gemm_w13(
    const float* __restrict__ A,
    const float* __restrict__ W0, const float* __restrict__ W1,
    float* __restrict__ C0, float* __restrict__ C1, int M, int K) {
  __shared__ GemmSmem sm;
  int mat = blockIdx.x / 22;
  int bn = (blockIdx.x % 22) * 128;
  const float* W = mat ? W1 : W0;
  float* C = mat ? C1 : C0;
  gemm_body<0>(sm, A, W, C, M, DFF_, K, 0, K, blockIdx.y * 128, bn);
}

// ---------------- per-head RMSNorm + RoPE on q and k, in place. one wave per (b,t,h)
__global__ __launch_bounds__(64) void qkrope_kernel(
    float* __restrict__ q, float* __restrict__ k,
    const float* __restrict__ qn, const float* __restrict__ kn) {
  int g = blockIdx.x;          // (b*T+t)*H + h
  int d = threadIdx.x;         // 0..63
  int bt = g / H_, hh = g % H_;
  int t = bt % T_;
  int s = scale_of(t);
  int pos = t - scale_start(s);
  int j = d & 31;
  float inv = expf(-0.28782313662425574f * (float)j);   // 10000^(-2j/64)
  float ang = (float)pos * inv;
  float c = cosf(ang), sn = sinf(ang);
  size_t off = (size_t)bt * D_ + hh * DH_ + d;

  {
    float x = q[off];
    float ss = x * x;
#pragma unroll
    for (int m = 32; m; m >>= 1) ss += __shfl_xor(ss, m);
    float r = rsqrtf(ss * (1.f / 64.f) + 1e-6f);
    float xn = x * r * qn[d];
    float part = __shfl_xor(xn, 32);
    q[off] = xn * c + ((d < 32) ? -part : part) * sn;
  }
  {
    float x = k[off];
    float ss = x * x;
#pragma unroll
    for (int m = 32; m; m >>= 1) ss += __shfl_xor(ss, m);
    float r = rsqrtf(ss * (1.f / 64.f) + 1e-6f);
    float xn = x * r * kn[d];
    float part = __shfl_xor(xn, 32);
    k[off] = xn * c + ((d < 32) ? -part : part) * sn;
  }
}

// ---------------- MFMA flash attention, split-bf16 (fp32-class accuracy)
__global__ __launch_bounds__(256) void attn_mfma(
    const float* __restrict__ q, const float* __restrict__ k,
    const float* __restrict__ v, float* __restrict__ o) {
  __shared__ unsigned short KsH[32][40], KsL[32][40];
  __shared__ unsigned short VtH[64][40], VtL[64][40];   // transposed: [dh][key]
  __shared__ unsigned short PsH[4][16][40], PsL[4][16][40];

  const int qt = blockIdx.x, hh = blockIdx.y, b = blockIdx.z;
  const int tx = threadIdx.x;
  const int w = tx >> 6, lane = tx & 63;
  const int fr = lane & 15, kh = lane >> 4;
  const int q0 = qt * 64;
  const int qw = q0 + w * 16;
  const int qg = qw + fr;

  const int e_lane = (qg < T_) ? scale_end(scale_of(qg)) : 0;
  const int qlast = min(q0 + 63, T_ - 1);
  const int e_blk = scale_end(scale_of(qlast));

  short8_t qfh[2], qfl[2];
  {
    bool okq = (qg < T_);
    const float* qp = q + ((size_t)(b * T_ + (okq ? qg : 0))) * D_ + hh * DH_;
#pragma unroll
    for (int c = 0; c < 2; ++c) {
      int d0 = c * 32 + kh * 8;
      float vv[8] = {0.f, 0.f, 0.f, 0.f, 0.f, 0.f, 0.f, 0.f};
      if (okq) {
        float4 t0 = *(const float4*)(qp + d0);
        float4 t1 = *(const float4*)(qp + d0 + 4);
        vv[0] = t0.x; vv[1] = t0.y; vv[2] = t0.z; vv[3] = t0.w;
        vv[4] = t1.x; vv[5] = t1.y; vv[6] = t1.z; vv[7] = t1.w;
      }
      cvt8(vv, qfh[c], qfl[c]);
    }
  }

  f32x4 oacc[4];
#pragma unroll
  for (int dt = 0; dt < 4; ++dt) oacc[dt] = {0.f, 0.f, 0.f, 0.f};
  float mrun = -INFINITY, lrun = 0.f;

  const int r_stage = tx >> 3;
  const int d_stage = (tx & 7) * 8;

  for (int j0 = 0; j0 < e_blk; j0 += 32) {
    __syncthreads();
    {
      int gk = j0 + r_stage;
      bool ok = gk < e_blk;
      size_t base = ((size_t)(b * T_ + (ok ? gk : 0))) * D_ + hh * DH_ + d_stage;
      float kv[8] = {0.f, 0.f, 0.f, 0.f, 0.f, 0.f, 0.f, 0.f};
      float vv[8] = {0.f, 0.f, 0.f, 0.f, 0.f, 0.f, 0.f, 0.f};
      if (ok) {
        float4 t0 = *(const float4*)(k + base);
        float4 t1 = *(const float4*)(k + base + 4);
        kv[0] = t0.x; kv[1] = t0.y; kv[2] = t0.z; kv[3] = t0.w;
        kv[4] = t1.x; kv[5] = t1.y; kv[6] = t1.z; kv[7] = t1.w;
        t0 = *(const float4*)(v + base);
        t1 = *(const float4*)(v + base + 4);
        vv[0] = t0.x; vv[1] = t0.y; vv[2] = t0.z; vv[3] = t0.w;
        vv[4] = t1.x; vv[5] = t1.y; vv[6] = t1.z; vv[7] = t1.w;
      }
      short8_t kh8, kl8;
      cvt8(kv, kh8, kl8);
      *(short8_t*)&KsH[r_stage][d_stage] = kh8;
      *(short8_t*)&KsL[r_stage][d_stage] = kl8;
#pragma unroll
      for (int i = 0; i < 8; ++i) {
        unsigned short h, l;
        cvt_hl(vv[i], h, l);
        VtH[d_stage + i][r_stage] = h;
        VtL[d_stage + i][r_stage] = l;
      }
    }
    __syncthreads();

    f32x4 st[2];
    st[0] = {0.f, 0.f, 0.f, 0.f};
    st[1] = {0.f, 0.f, 0.f, 0.f};
#pragma unroll
    for (int kt = 0; kt < 2; ++kt) {
#pragma unroll
      for (int c = 0; c < 2; ++c) {
        short8_t kfh = *(const short8_t*)&KsH[kt * 16 + fr][c * 32 + kh * 8];
        short8_t kfl = *(const short8_t*)&KsL[kt * 16 + fr][c * 32 + kh * 8];
        st[kt] = __builtin_amdgcn_mfma_f32_16x16x32_bf16(kfh, qfh[c], st[kt], 0, 0, 0);
        st[kt] = __builtin_amdgcn_mfma_f32_16x16x32_bf16(kfh, qfl[c], st[kt], 0, 0, 0);
        st[kt] = __builtin_amdgcn_mfma_f32_16x16x32_bf16(kfl, qfh[c], st[kt], 0, 0, 0);
      }
    }

    float sc[8];
    float tmax = -INFINITY;
#pragma unroll
    for (int kt = 0; kt < 2; ++kt)
#pragma unroll
      for (int j = 0; j < 4; ++j) {
        float s = st[kt][j] * 0.125f;
        int keyg = j0 + kt * 16 + kh * 4 + j;
        if (keyg >= e_lane) s = -INFINITY;
        sc[kt * 4 + j] = s;
        tmax = fmaxf(tmax, s);
      }
    tmax = fmaxf(tmax, __shfl_xor(tmax, 16));
    tmax = fmaxf(tmax, __shfl_xor(tmax, 32));
    float m_new = fmaxf(mrun, tmax);
    float alpha;
    float pp[8];
    if (m_new == -INFINITY) {
      alpha = 1.f;
#pragma unroll
      for (int i = 0; i < 8; ++i) pp[i] = 0.f;
    } else {
      alpha = (mrun == -INFINITY) ? 0.f : expf(mrun - m_new);
#pragma unroll
      for (int i = 0; i < 8; ++i) pp[i] = (sc[i] == -INFINITY) ? 0.f : expf(sc[i] - m_new);
    }
    float psum = 0.f;
#pragma unroll
    for (int i = 0; i < 8; ++i) psum += pp[i];
    psum += __shfl_xor(psum, 16);
    psum += __shfl_xor(psum, 32);
    lrun = lrun * alpha + psum;
    mrun = m_new;

#pragma unroll
    for (int kt = 0; kt < 2; ++kt) {
      ushort4 phv, plv;
      unsigned short h, l;
      cvt_hl(pp[kt * 4 + 0], h, l); phv.x = h; plv.x = l;
      cvt_hl(pp[kt * 4 + 1], h, l); phv.y = h; plv.y = l;
      cvt_hl(pp[kt * 4 + 2], h, l); phv.z = h; plv.z = l;
      cvt_hl(pp[kt * 4 + 3], h, l); phv.w = h; plv.w = l;
      *(ushort4*)&PsH[w][fr][kt * 16 + kh * 4] = phv;
      *(ushort4*)&PsL[w][fr][kt * 16 + kh * 4] = plv;
    }

    float al0 = __shfl(alpha, kh * 4 + 0);
    float al1 = __shfl(alpha, kh * 4 + 1);
    float al2 = __shfl(alpha, kh * 4 + 2);
    float al3 = __shfl(alpha, kh * 4 + 3);
#pragma unroll
    for (int dt = 0; dt < 4; ++dt) {
      oacc[dt][0] *= al0; oacc[dt][1] *= al1;
      oacc[dt][2] *= al2; oacc[dt][3] *= al3;
    }

    short8_t pah = *(const short8_t*)&PsH[w][fr][kh * 8];
    short8_t pal = *(const short8_t*)&PsL[w][fr][kh * 8];
#pragma unroll
    for (int dt = 0; dt < 4; ++dt) {
      short8_t vbh = *(const short8_t*)&VtH[dt * 16 + fr][kh * 8];
      short8_t vbl = *(const short8_t*)&VtL[dt * 16 + fr][kh * 8];
      oacc[dt] = __builtin_amdgcn_mfma_f32_16x16x32_bf16(pah, vbh, oacc[dt], 0, 0, 0);
      oacc[dt] = __builtin_amdgcn_mfma_f32_16x16x32_bf16(pal, vbh, oacc[dt], 0, 0, 0);
      oacc[dt] = __builtin_amdgcn_mfma_f32_16x16x32_bf16(pah, vbl, oacc[dt], 0, 0, 0);
    }
  }

  float li0 = __shfl(lrun, kh * 4 + 0);
  float li1 = __shfl(lrun, kh * 4 + 1);
  float li2 = __shfl(lrun, kh * 4 + 2);
  float li3 = __shfl(lrun, kh * 4 + 3);
  float linv[4] = {1.f / li0, 1.f / li1, 1.f / li2, 1.f / li3};
#pragma unroll
  for (int j = 0; j < 4; ++j) {
    int qrow = qw + kh * 4 + j;
    if (qrow >= T_) continue;
    size_t base = ((size_t)(b * T_ + qrow)) * D_ + hh * DH_;
#pragma unroll
    for (int dt = 0; dt < 4; ++dt)
      o[base + dt * 16 + fr] = oacc[dt][j] * linv[j];
  }
}

// ---------------- h = rms(h + f) * g variants (f = sum of partials)
__global__ __launch_bounds__(256) void rmsadd_kernel(
    float* __restrict__ h, const float* __restrict__ f, const float* __restrict__ g) {
  int row = blockIdx.x;
  int tx = threadIdx.x;
  size_t base = (size_t)row * D_;
  float x[4];
  float ss = 0.f;
#pragma unroll
  for (int i = 0; i < 4; ++i) {
    int d = tx + 256 * i;
    x[i] = h[base + d] + f[base + d];
    ss += x[i] * x[i];
  }
  __shared__ float red[4];
#pragma unroll
  for (int m = 32; m; m >>= 1) ss += __shfl_xor(ss, m);
  if ((tx & 63) == 0) red[tx >> 6] = ss;
  __syncthreads();
  float tot = red[0] + red[1] + red[2] + red[3];
  float r = rsqrtf(tot * (1.f / (float)D_) + 1e-6f);
#pragma unroll
  for (int i = 0; i < 4; ++i) {
    int d = tx + 256 * i;
    h[base + d] = x[i] * r * g[d];
  }
}

__global__ __launch_bounds__(256) void rmsadd2_kernel(
    float* __restrict__ h, const float* __restrict__ f0, const float* __restrict__ f1,
    const float* __restrict__ g) {
  int row = blockIdx.x;
  int tx = threadIdx.x;
  size_t base = (size_t)row * D_;
  float x[4];
  float ss = 0.f;
#pragma unroll
  for (int i = 0; i < 4; ++i) {
    int d = tx + 256 * i;
    x[i] = h[base + d] + (f0[base + d] + f1[base + d]);
    ss += x[i] * x[i];
  }
  __shared__ float red[4];
#pragma unroll
  for (int m = 32; m; m >>= 1) ss += __shfl_xor(ss, m);
  if ((tx & 63) == 0) red[tx >> 6] = ss;
  __syncthreads();
  float tot = red[0] + red[1] + red[2] + red[3];
  float r = rsqrtf(tot * (1.f / (float)D_) + 1e-6f);
#pragma unroll
  for (int i = 0; i < 4; ++i) {
    int d = tx + 256 * i;
    h[base + d] = x[i] * r * g[d];
  }
}

__global__ __launch_bounds__(256) void rmsadd4_kernel(
    float* __restrict__ h, const float* __restrict__ f0, const float* __restrict__ f1,
    const float* __restrict__ f2, const float* __restrict__ f3, const float* __restrict__ g) {
  int row = blockIdx.x;
  int tx = threadIdx.x;
  size_t base = (size_t)row * D_;
  float x[4];
  float ss = 0.f;
#pragma unroll
  for (int i = 0; i < 4; ++i) {
    int d = tx + 256 * i;
    x[i] = h[base + d] + ((f0[base + d] + f1[base + d]) + (f2[base + d] + f3[base + d]));
    ss += x[i] * x[i];
  }
  __shared__ float red[4];
#pragma unroll
  for (int m = 32; m; m >>= 1) ss += __shfl_xor(ss, m);
  if ((tx & 63) == 0) red[tx >> 6] = ss;
  __syncthreads();
  float tot = red[0] + red[1] + red[2] + red[3];
  float r = rsqrtf(tot * (1.f / (float)D_) + 1e-6f);
#pragma unroll
  for (int i = 0; i < 4; ++i) {
    int d = tx + 256 * i;
    h[base + d] = x[i] * r * g[d];
  }
}

// ---------------- a1 = silu(a1) * a3
__global__ __launch_bounds__(256) void swiglu_kernel(
    float* __restrict__ a1, const float* __restrict__ a3, size_t n) {
  size_t idx = (size_t)blockIdx.x * 256 + threadIdx.x;
  if (idx < n) {
    float x = a1[idx];
    float sig = 1.f / (1.f + expf(-x));
    a1[idx] = x * sig * a3[idx];
  }
}

// ---------------- per-row logsumexp + CE partials
__global__ __launch_bounds__(256) void loss_kernel(
    const float* __restrict__ logits, const int* __restrict__ tokens, float* __restrict__ acc) {
  int row = blockIdx.x;
  int tx = threadIdx.x;
  const float* lr = logits + (size_t)row * V_;
  __shared__ float red[4];

  float mx = -INFINITY;
  for (int jv = tx; jv < V_; jv += 256) mx = fmaxf(mx, lr[jv]);
#pragma unroll
  for (int m = 32; m; m >>= 1) mx = fmaxf(mx, __shfl_xor(mx, m));
  if ((tx & 63) == 0) red[tx >> 6] = mx;
  __syncthreads();
  mx = fmaxf(fmaxf(red[0], red[1]), fmaxf(red[2], red[3]));
  __syncthreads();

  float se = 0.f;
  for (int jv = tx; jv < V_; jv += 256) se += expf(lr[jv] - mx);
#pragma unroll
  for (int m = 32; m; m >>= 1) se += __shfl_xor(se, m);
  if ((tx & 63) == 0) red[tx >> 6] = se;
  __syncthreads();
  se = red[0] + red[1] + red[2] + red[3];

  if (tx == 0) {
    float lse = mx + logf(se);
    float lt = lr[tokens[row]];
    atomicAdd(&acc[0], lse - lt);
    atomicAdd(&acc[1], lse * lse);
  }
}

__global__ void zero_acc_kernel(float* acc) {
  if (threadIdx.x < 2) acc[threadIdx.x] = 0.f;
}

__global__ void finalize_kernel(const float* __restrict__ acc, float* __restrict__ out) {
  out[0] = acc[0] * (1.f / (float)BT_) + 1e-4f * acc[1] * (1.f / (float)BT_);
}

static inline dim3 gemm_grid(int M, int N) {
  return dim3((unsigned)((N + 127) / 128), (unsigned)((M + 127) / 128));
}

extern "C" void kernel_launch(void* const* d_in, const int* in_sizes, int n_in,
                              void* d_out, int out_size, void* d_ws, size_t ws_size,
                              hipStream_t stream) {
  const int* i0 = (const int*)d_in[0];
  const int* i1 = (const int*)d_in[1];
  const int* i2 = (const int*)d_in[2];
  const int* i3 = (const int*)d_in[3];
  const int* i4 = (const int*)d_in[4];
  const int* i5 = (const int*)d_in[5];
  const float* temb = (const float*)d_in[6];
  const float* semb = (const float*)d_in[7];
  const float* stok = (const float*)d_in[8];
  const float* wq = (const float*)d_in[9];
  const float* wk = (const float*)d_in[10];
  const float* wv = (const float*)d_in[11];
  const float* wo = (const float*)d_in[12];
  const float* qn = (const float*)d_in[13];
  const float* kn = (const float*)d_in[14];
  const float* n1 = (const float*)d_in[15];
  const float* n2 = (const float*)d_in[16];
  const float* w1 = (const float*)d_in[17];
  const float* w3 = (const float*)d_in[18];
  const float* w2 = (const float*)d_in[19];

  const size_t S  = (size_t)BT_ * D_;     // 2,795,520 floats
  const size_t F  = (size_t)BT_ * DFF_;   // 7,512,960 floats
  float* ws = (float*)d_ws;
  float* h  = ws;
  float* R  = ws + S;                      // union region [2F]
  // attention phase
  float* qb   = R;
  float* kb   = R + S;
  float* vb   = R + 2 * S;
  float* ob   = R + 4 * S;                 // attn output (R+4S..R+5S < R+2F)
  // wo split-K partials: R..4S (qb/kb/vb dead after attn; R+3S unused)
  float* wop0 = R;
  float* wop1 = R + S;
  float* wop2 = R + 2 * S;
  float* wop3 = R + 3 * S;
  // FFN phase
  float* a1   = R;                         // [F]
  float* a3   = R + F;                     // consumed by swiglu
  float* w2p0 = R + F;                     // w2 split-K partials (a3 dead)
  float* w2p1 = R + F + S;
  float* logits = R;
  int*   tokens = (int*)(ws + S + 2 * F);
  float* acc    = ws + S + 2 * F + ((BT_ + 15) & ~1);

  dim3 blk(256);
  embed_kernel<<<BT_, blk, 0, stream>>>(i0, i1, i2, i3, i4, i5, temb, semb, stok, h, tokens);

  for (int l = 0; l < NL_; ++l) {
    const float* wql = wq + (size_t)l * D_ * D_;
    const float* wkl = wk + (size_t)l * D_ * D_;
    const float* wvl = wv + (size_t)l * D_ * D_;
    const float* wol = wo + (size_t)l * D_ * D_;
    const float* w1l = w1 + (size_t)l * D_ * DFF_;
    const float* w3l = w3 + (size_t)l * D_ * DFF_;
    const float* w2l = w2 + (size_t)l * DFF_ * D_;

    gemm_qkv<<<dim3(24, (BT_ + 127) / 128), blk, 0, stream>>>(h, wql, wkl, wvl, qb, kb, vb, BT_, D_);
    qkrope_kernel<<<BT_ * H_, dim3(64), 0, stream>>>(qb, kb, qn + (size_t)l * DH_, kn + (size_t)l * DH_);
    attn_mfma<<<dim3((T_ + 63) / 64, H_, B_), blk, 0, stream>>>(qb, kb, vb, ob);
    // wo: split-K x4 (K=1024 -> 4 chunks of 256)
    gemm_splitk<0><<<dim3(8, (BT_ + 127) / 128, 4), blk, 0, stream>>>(
        ob, wol, wop0, wop1, wop2, wop3, BT_, D_, D_, 256);
    rmsadd4_kernel<<<BT_, blk, 0, stream>>>(h, wop0, wop1, wop2, wop3, n1 + (size_t)l * D_);
    gemm_w13<<<dim3(44, (BT_ + 127) / 128), blk, 0, stream>>>(h, w1l, w3l, a1, a3, BT_, D_);
    {
      size_t n = (size_t)BT_ * DFF_;
      swiglu_kernel<<<(unsigned)((n + 255) / 256), blk, 0, stream>>>(a1, a3, n);
    }
    // w2: split-K x2 (K=2752 -> 2 chunks of 1376)
    gemm_splitk<0><<<dim3(8, (BT_ + 127) / 128, 2), blk, 0, stream>>>(
        a1, w2l, w2p0, w2p1, nullptr, nullptr, BT_, D_, DFF_, 1376);
    rmsadd2_kernel<<<BT_, blk, 0, stream>>>(h, w2p0, w2p1, n2 + (size_t)l * D_);
  }

  gemm_mfma<1><<<gemm_grid(BT_, V_), blk, 0, stream>>>(h, temb, logits, BT_, V_, D_);
  zero_acc_kernel<<<1, 64, 0, stream>>>(acc);
  loss_kernel<<<BT_, blk, 0, stream>>>(logits, tokens, acc);
  finalize_kernel<<<1, 1, 0, stream>>>(acc, (float*)d_out);
}

// Round 5
// 7596.109 us; speedup vs baseline: 2.0415x; 2.0415x over previous
//
#include <hip/hip_runtime.h>
#include <cstdint>
#include <cstddef>

#define V_   4096
#define D_   1024
#define H_   16
#define NL_  12
#define DFF_ 2752
#define DH_  64
#define T_   1365
#define B_   2
#define BT_  (B_ * T_)

typedef __attribute__((ext_vector_type(8))) short short8_t;  // 8 bf16 (4 VGPRs)
typedef __attribute__((ext_vector_type(4))) float f32x4;

static __device__ __forceinline__ int scale_of(int t) {
  return (t < 1) ? 0 : (t < 5) ? 1 : (t < 21) ? 2 : (t < 85) ? 3 : (t < 341) ? 4 : 5;
}
static __device__ __forceinline__ int scale_start(int s) {
  return (s == 0) ? 0 : (s == 1) ? 1 : (s == 2) ? 5 : (s == 3) ? 21 : (s == 4) ? 85 : 341;
}
static __device__ __forceinline__ int scale_end(int s) {
  return (s == 0) ? 1 : (s == 1) ? 5 : (s == 2) ? 21 : (s == 3) ? 85 : (s == 4) ? 341 : 1365;
}

// split fp32 x ≈ hi + lo (both bf16, RNE). Dropped lo*lo in products ≈ 2^-18 rel.
static __device__ __forceinline__ void cvt_hl(float x, unsigned short& h, unsigned short& l) {
  uint32_t b = __builtin_bit_cast(uint32_t, x);
  uint32_t hb = b + 0x7FFFu + ((b >> 16) & 1u);
  h = (unsigned short)(hb >> 16);
  float hf = __builtin_bit_cast(float, hb & 0xFFFF0000u);
  float r = x - hf;
  uint32_t rb = __builtin_bit_cast(uint32_t, r);
  rb += 0x7FFFu + ((rb >> 16) & 1u);
  l = (unsigned short)(rb >> 16);
}

static __device__ __forceinline__ void cvt8(const float* vv, short8_t& h8, short8_t& l8) {
#pragma unroll
  for (int j = 0; j < 8; ++j) {
    unsigned short h, l;
    cvt_hl(vv[j], h, l);
    h8[j] = (short)h;
    l8[j] = (short)l;
  }
}

// raw barriers: do NOT drain vmcnt (keeps prefetch loads in flight across barriers)
static __device__ __forceinline__ void bar_lgkm() {
  asm volatile("s_waitcnt lgkmcnt(0)" ::: "memory");
  __builtin_amdgcn_sched_barrier(0);
  __builtin_amdgcn_s_barrier();
  __builtin_amdgcn_sched_barrier(0);
}
static __device__ __forceinline__ void bar_plain() {
  __builtin_amdgcn_sched_barrier(0);
  __builtin_amdgcn_s_barrier();
  __builtin_amdgcn_sched_barrier(0);
}

// ---------------- embed
__global__ __launch_bounds__(256) void embed_kernel(
    const int* __restrict__ i0, const int* __restrict__ i1, const int* __restrict__ i2,
    const int* __restrict__ i3, const int* __restrict__ i4, const int* __restrict__ i5,
    const float* __restrict__ tok_emb, const float* __restrict__ scl_emb,
    const float* __restrict__ start_tok, float* __restrict__ h, int* __restrict__ tokens) {
  int row = blockIdx.x;              // b*T + t
  int b = row / T_, t = row % T_;
  int s = scale_of(t);
  int st = scale_start(s);
  int sz = scale_end(s) - st;
  const int* ip = (s == 0) ? i0 : (s == 1) ? i1 : (s == 2) ? i2 : (s == 3) ? i3 : (s == 4) ? i4 : i5;
  int tok = ip[b * sz + (t - st)];
  if (threadIdx.x == 0) tokens[row] = tok;
  const float* base = (t == 0) ? start_tok : (tok_emb + (size_t)tok * D_);
  size_t ho = (size_t)row * D_;
  for (int d = threadIdx.x; d < D_; d += 256)
    h[ho + d] = base[d] + scl_emb[s * D_ + d];
}

// ---------------- split-bf16 MFMA GEMM body, software-pipelined.
// NT=0: W is [K,N]; NT=1: W is [N,K]. 128x128 tile, BK=32, 4 waves of 64x64.
// Single LDS buffer, reg-staged prefetch of tile k+1 issued before MFMA of tile k.
// NOTE: no min-occupancy launch bound — prefetch regs (pa/pb) must stay in VGPRs
// (round-4 lesson: (256,3) bound pinned VGPR=84 and spilled ~400 MB/dispatch to scratch).
struct GemmSmem {
  unsigned short AsH[128][40];
  unsigned short AsL[128][40];
  unsigned short BsH[128][40];
  unsigned short BsL[128][40];
};

template <int NT>
static __device__ __forceinline__ void gemm_body(
    GemmSmem& sm, const float* __restrict__ A, const float* __restrict__ W,
    float* __restrict__ C, int M, int N, int K, int kbase, int klen, int bm, int bn) {
  const int tx = threadIdx.x;
  const int wave = tx >> 6;
  const int lane = tx & 63;
  const int wr = (wave >> 1) * 64;
  const int wc = (wave & 1) * 64;
  const int fr = lane & 15;
  const int kh = lane >> 4;

  float4 pa[4];
  float pb[4][4];

  auto load_tile = [&](int k0) {
#pragma unroll
    for (int it = 0; it < 4; ++it) {
      int slot = it * 256 + tx;
      int m = slot >> 3, kq = slot & 7;
      int gm = bm + m;
      if (gm < M) pa[it] = *(const float4*)(A + (size_t)gm * K + (k0 + 4 * kq));
      else        pa[it] = float4{0.f, 0.f, 0.f, 0.f};
    }
#pragma unroll
    for (int it = 0; it < 4; ++it) {
      int slot = it * 256 + tx;
      if constexpr (NT) {
        int n = slot >> 3, kq = slot & 7;
        int gn = bn + n;
        float4 t = {0.f, 0.f, 0.f, 0.f};
        if (gn < N) t = *(const float4*)(W + (size_t)gn * K + (k0 + 4 * kq));
        pb[it][0] = t.x; pb[it][1] = t.y; pb[it][2] = t.z; pb[it][3] = t.w;
      } else {
        int n = slot & 127, kq = slot >> 7;
        int gn = bn + n;
        if (gn < N) {
#pragma unroll
          for (int r = 0; r < 4; ++r)
            pb[it][r] = W[(size_t)(k0 + 4 * kq + r) * N + gn];
        } else {
          pb[it][0] = pb[it][1] = pb[it][2] = pb[it][3] = 0.f;
        }
      }
    }
  };

  auto store_tile = [&]() {
#pragma unroll
    for (int it = 0; it < 4; ++it) {
      int slot = it * 256 + tx;
      int m = slot >> 3, kq = slot & 7;
      ushort4 hh, ll;
      cvt_hl(pa[it].x, hh.x, ll.x); cvt_hl(pa[it].y, hh.y, ll.y);
      cvt_hl(pa[it].z, hh.z, ll.z); cvt_hl(pa[it].w, hh.w, ll.w);
      *(ushort4*)&sm.AsH[m][4 * kq] = hh;
      *(ushort4*)&sm.AsL[m][4 * kq] = ll;
    }
#pragma unroll
    for (int it = 0; it < 4; ++it) {
      int slot = it * 256 + tx;
      int n, kq;
      if constexpr (NT) { n = slot >> 3; kq = slot & 7; }
      else              { n = slot & 127; kq = slot >> 7; }
      ushort4 hh, ll;
      cvt_hl(pb[it][0], hh.x, ll.x); cvt_hl(pb[it][1], hh.y, ll.y);
      cvt_hl(pb[it][2], hh.z, ll.z); cvt_hl(pb[it][3], hh.w, ll.w);
      *(ushort4*)&sm.BsH[n][4 * kq] = hh;
      *(ushort4*)&sm.BsL[n][4 * kq] = ll;
    }
  };

  f32x4 acc[4][4];
#pragma unroll
  for (int mi = 0; mi < 4; ++mi)
#pragma unroll
    for (int ni = 0; ni < 4; ++ni) acc[mi][ni] = {0.f, 0.f, 0.f, 0.f};

  const int nsteps = klen >> 5;
  load_tile(kbase);
  store_tile();

  for (int st = 0; st < nsteps; ++st) {
    bar_lgkm();   // LDS writes of this tile complete, all waves arrived

    short8_t ah[4], al[4], bh[4], bl[4];
#pragma unroll
    for (int mi = 0; mi < 4; ++mi) {
      int r = wr + mi * 16 + fr;
      ah[mi] = *(const short8_t*)&sm.AsH[r][8 * kh];
      al[mi] = *(const short8_t*)&sm.AsL[r][8 * kh];
    }
#pragma unroll
    for (int ni = 0; ni < 4; ++ni) {
      int c = wc + ni * 16 + fr;
      bh[ni] = *(const short8_t*)&sm.BsH[c][8 * kh];
      bl[ni] = *(const short8_t*)&sm.BsL[c][8 * kh];
    }

    if (st + 1 < nsteps) load_tile(kbase + (st + 1) * 32);  // prefetch: latency hides under MFMA

#pragma unroll
    for (int mi = 0; mi < 4; ++mi)
#pragma unroll
      for (int ni = 0; ni < 4; ++ni) {
        acc[mi][ni] = __builtin_amdgcn_mfma_f32_16x16x32_bf16(ah[mi], bh[ni], acc[mi][ni], 0, 0, 0);
        acc[mi][ni] = __builtin_amdgcn_mfma_f32_16x16x32_bf16(ah[mi], bl[ni], acc[mi][ni], 0, 0, 0);
        acc[mi][ni] = __builtin_amdgcn_mfma_f32_16x16x32_bf16(al[mi], bh[ni], acc[mi][ni], 0, 0, 0);
      }

    bar_plain();  // all waves done reading LDS (implied by their MFMA lgkm waits)
    if (st + 1 < nsteps) store_tile();
  }

  const int rsub = (lane >> 4) * 4;
#pragma unroll
  for (int mi = 0; mi < 4; ++mi) {
#pragma unroll
    for (int j = 0; j < 4; ++j) {
      int gm = bm + wr + mi * 16 + rsub + j;
      if (gm >= M) continue;
      float* crow = C + (size_t)gm * N;
#pragma unroll
      for (int ni = 0; ni < 4; ++ni) {
        int gn = bn + wc + ni * 16 + fr;
        if (gn < N) crow[gn] = acc[mi][ni][j];
      }
    }
  }
}

template <int NT>
__global__ __launch_bounds__(256) void gemm_mfma(
    const float* __restrict__ A, const float* __restrict__ W, float* __restrict__ C,
    int M, int N, int K) {
  __shared__ GemmSmem sm;
  gemm_body<NT>(sm, A, W, C, M, N, K, 0, K, blockIdx.y * 128, blockIdx.x * 128);
}

// split-K: blockIdx.z = chunk; each chunk writes its own partial C
template <int NT>
__global__ __launch_bounds__(256) void gemm_splitk(
    const float* __restrict__ A, const float* __restrict__ W,
    float* __restrict__ C0, float* __restrict__ C1,
    float* __restrict__ C2, float* __restrict__ C3,
    int M, int N, int K, int klen) {
  __shared__ GemmSmem sm;
  int sk = blockIdx.z;
  float* C = (sk == 0) ? C0 : (sk == 1) ? C1 : (sk == 2) ? C2 : C3;
  gemm_body<NT>(sm, A, W, C, M, N, K, sk * klen, klen, blockIdx.y * 128, blockIdx.x * 128);
}

// fused QKV: grid.x = 24 (3 mats x 8 tiles of N=1024)
__global__ __launch_bounds__(256) void gemm_qkv(
    const float* __restrict__ A,
    const float* __restrict__ W0, const float* __restrict__ W1, const float* __restrict__ W2,
    float* __restrict__ C0, float* __restrict__ C1, float* __restrict__ C2, int M, int K) {
  __shared__ GemmSmem sm;
  int mat = blockIdx.x >> 3;
  int bn = (blockIdx.x & 7) * 128;
  const float* W = (mat == 0) ? W0 : (mat == 1) ? W1 : W2;
  float* C = (mat == 0) ? C0 : (mat == 1) ? C1 : C2;
  gemm_body<0>(sm, A, W, C, M, 1024, K, 0, K, blockIdx.y * 128, bn);
}

// fused w1/w3: grid.x = 44 (2 mats x 22 tiles of N=2752)
__global__ __launch_bounds__(256) void gemm_w13(
    const float* __restrict__ A,
    const float* __restrict__ W0, const float* __restrict__ W1,
    float* __restrict__ C0, float* __restrict__ C1, int M, int K) {
  __shared__ GemmSmem sm;
  int mat = blockIdx.x / 22;
  int bn = (blockIdx.x % 22) * 128;
  const float* W = mat ? W1 : W0;
  float* C = mat ? C1 : C0;
  gemm_body<0>(sm, A, W, C, M, DFF_, K, 0, K, blockIdx.y * 128, bn);
}

// ---------------- per-head RMSNorm + RoPE on q and k, in place. one wave per (b,t,h)
__global__ __launch_bounds__(64) void qkrope_kernel(
    float* __restrict__ q, float* __restrict__ k,
    const float* __restrict__ qn, const float* __restrict__ kn) {
  int g = blockIdx.x;          // (b*T+t)*H + h
  int d = threadIdx.x;         // 0..63
  int bt = g / H_, hh = g % H_;
  int t = bt % T_;
  int s = scale_of(t);
  int pos = t - scale_start(s);
  int j = d & 31;
  float inv = expf(-0.28782313662425574f * (float)j);   // 10000^(-2j/64)
  float ang = (float)pos * inv;
  float c = cosf(ang), sn = sinf(ang);
  size_t off = (size_t)bt * D_ + hh * DH_ + d;

  {
    float x = q[off];
    float ss = x * x;
#pragma unroll
    for (int m = 32; m; m >>= 1) ss += __shfl_xor(ss, m);
    float r = rsqrtf(ss * (1.f / 64.f) + 1e-6f);
    float xn = x * r * qn[d];
    float part = __shfl_xor(xn, 32);
    q[off] = xn * c + ((d < 32) ? -part : part) * sn;
  }
  {
    float x = k[off];
    float ss = x * x;
#pragma unroll
    for (int m = 32; m; m >>= 1) ss += __shfl_xor(ss, m);
    float r = rsqrtf(ss * (1.f / 64.f) + 1e-6f);
    float xn = x * r * kn[d];
    float part = __shfl_xor(xn, 32);
    k[off] = xn * c + ((d < 32) ? -part : part) * sn;
  }
}

// ---------------- MFMA flash attention, split-bf16 (fp32-class accuracy)
__global__ __launch_bounds__(256) void attn_mfma(
    const float* __restrict__ q, const float* __restrict__ k,
    const float* __restrict__ v, float* __restrict__ o) {
  __shared__ unsigned short KsH[32][40], KsL[32][40];
  __shared__ unsigned short VtH[64][40], VtL[64][40];   // transposed: [dh][key]
  __shared__ unsigned short PsH[4][16][40], PsL[4][16][40];

  const int qt = blockIdx.x, hh = blockIdx.y, b = blockIdx.z;
  const int tx = threadIdx.x;
  const int w = tx >> 6, lane = tx & 63;
  const int fr = lane & 15, kh = lane >> 4;
  const int q0 = qt * 64;
  const int qw = q0 + w * 16;
  const int qg = qw + fr;

  const int e_lane = (qg < T_) ? scale_end(scale_of(qg)) : 0;
  const int qlast = min(q0 + 63, T_ - 1);
  const int e_blk = scale_end(scale_of(qlast));

  short8_t qfh[2], qfl[2];
  {
    bool okq = (qg < T_);
    const float* qp = q + ((size_t)(b * T_ + (okq ? qg : 0))) * D_ + hh * DH_;
#pragma unroll
    for (int c = 0; c < 2; ++c) {
      int d0 = c * 32 + kh * 8;
      float vv[8] = {0.f, 0.f, 0.f, 0.f, 0.f, 0.f, 0.f, 0.f};
      if (okq) {
        float4 t0 = *(const float4*)(qp + d0);
        float4 t1 = *(const float4*)(qp + d0 + 4);
        vv[0] = t0.x; vv[1] = t0.y; vv[2] = t0.z; vv[3] = t0.w;
        vv[4] = t1.x; vv[5] = t1.y; vv[6] = t1.z; vv[7] = t1.w;
      }
      cvt8(vv, qfh[c], qfl[c]);
    }
  }

  f32x4 oacc[4];
#pragma unroll
  for (int dt = 0; dt < 4; ++dt) oacc[dt] = {0.f, 0.f, 0.f, 0.f};
  float mrun = -INFINITY, lrun = 0.f;

  const int r_stage = tx >> 3;
  const int d_stage = (tx & 7) * 8;

  for (int j0 = 0; j0 < e_blk; j0 += 32) {
    __syncthreads();
    {
      int gk = j0 + r_stage;
      bool ok = gk < e_blk;
      size_t base = ((size_t)(b * T_ + (ok ? gk : 0))) * D_ + hh * DH_ + d_stage;
      float kv[8] = {0.f, 0.f, 0.f, 0.f, 0.f, 0.f, 0.f, 0.f};
      float vv[8] = {0.f, 0.f, 0.f, 0.f, 0.f, 0.f, 0.f, 0.f};
      if (ok) {
        float4 t0 = *(const float4*)(k + base);
        float4 t1 = *(const float4*)(k + base + 4);
        kv[0] = t0.x; kv[1] = t0.y; kv[2] = t0.z; kv[3] = t0.w;
        kv[4] = t1.x; kv[5] = t1.y; kv[6] = t1.z; kv[7] = t1.w;
        t0 = *(const float4*)(v + base);
        t1 = *(const float4*)(v + base + 4);
        vv[0] = t0.x; vv[1] = t0.y; vv[2] = t0.z; vv[3] = t0.w;
        vv[4] = t1.x; vv[5] = t1.y; vv[6] = t1.z; vv[7] = t1.w;
      }
      short8_t kh8, kl8;
      cvt8(kv, kh8, kl8);
      *(short8_t*)&KsH[r_stage][d_stage] = kh8;
      *(short8_t*)&KsL[r_stage][d_stage] = kl8;
#pragma unroll
      for (int i = 0; i < 8; ++i) {
        unsigned short h, l;
        cvt_hl(vv[i], h, l);
        VtH[d_stage + i][r_stage] = h;
        VtL[d_stage + i][r_stage] = l;
      }
    }
    __syncthreads();

    f32x4 st[2];
    st[0] = {0.f, 0.f, 0.f, 0.f};
    st[1] = {0.f, 0.f, 0.f, 0.f};
#pragma unroll
    for (int kt = 0; kt < 2; ++kt) {
#pragma unroll
      for (int c = 0; c < 2; ++c) {
        short8_t kfh = *(const short8_t*)&KsH[kt * 16 + fr][c * 32 + kh * 8];
        short8_t kfl = *(const short8_t*)&KsL[kt * 16 + fr][c * 32 + kh * 8];
        st[kt] = __builtin_amdgcn_mfma_f32_16x16x32_bf16(kfh, qfh[c], st[kt], 0, 0, 0);
        st[kt] = __builtin_amdgcn_mfma_f32_16x16x32_bf16(kfh, qfl[c], st[kt], 0, 0, 0);
        st[kt] = __builtin_amdgcn_mfma_f32_16x16x32_bf16(kfl, qfh[c], st[kt], 0, 0, 0);
      }
    }

    float sc[8];
    float tmax = -INFINITY;
#pragma unroll
    for (int kt = 0; kt < 2; ++kt)
#pragma unroll
      for (int j = 0; j < 4; ++j) {
        float s = st[kt][j] * 0.125f;
        int keyg = j0 + kt * 16 + kh * 4 + j;
        if (keyg >= e_lane) s = -INFINITY;
        sc[kt * 4 + j] = s;
        tmax = fmaxf(tmax, s);
      }
    tmax = fmaxf(tmax, __shfl_xor(tmax, 16));
    tmax = fmaxf(tmax, __shfl_xor(tmax, 32));
    float m_new = fmaxf(mrun, tmax);
    float alpha;
    float pp[8];
    if (m_new == -INFINITY) {
      alpha = 1.f;
#pragma unroll
      for (int i = 0; i < 8; ++i) pp[i] = 0.f;
    } else {
      alpha = (mrun == -INFINITY) ? 0.f : expf(mrun - m_new);
#pragma unroll
      for (int i = 0; i < 8; ++i) pp[i] = (sc[i] == -INFINITY) ? 0.f : expf(sc[i] - m_new);
    }
    float psum = 0.f;
#pragma unroll
    for (int i = 0; i < 8; ++i) psum += pp[i];
    psum += __shfl_xor(psum, 16);
    psum += __shfl_xor(psum, 32);
    lrun = lrun * alpha + psum;
    mrun = m_new;

#pragma unroll
    for (int kt = 0; kt < 2; ++kt) {
      ushort4 phv, plv;
      unsigned short h, l;
      cvt_hl(pp[kt * 4 + 0], h, l); phv.x = h; plv.x = l;
      cvt_hl(pp[kt * 4 + 1], h, l); phv.y = h; plv.y = l;
      cvt_hl(pp[kt * 4 + 2], h, l); phv.z = h; plv.z = l;
      cvt_hl(pp[kt * 4 + 3], h, l); phv.w = h; plv.w = l;
      *(ushort4*)&PsH[w][fr][kt * 16 + kh * 4] = phv;
      *(ushort4*)&PsL[w][fr][kt * 16 + kh * 4] = plv;
    }

    float al0 = __shfl(alpha, kh * 4 + 0);
    float al1 = __shfl(alpha, kh * 4 + 1);
    float al2 = __shfl(alpha, kh * 4 + 2);
    float al3 = __shfl(alpha, kh * 4 + 3);
#pragma unroll
    for (int dt = 0; dt < 4; ++dt) {
      oacc[dt][0] *= al0; oacc[dt][1] *= al1;
      oacc[dt][2] *= al2; oacc[dt][3] *= al3;
    }

    short8_t pah = *(const short8_t*)&PsH[w][fr][kh * 8];
    short8_t pal = *(const short8_t*)&PsL[w][fr][kh * 8];
#pragma unroll
    for (int dt = 0; dt < 4; ++dt) {
      short8_t vbh = *(const short8_t*)&VtH[dt * 16 + fr][kh * 8];
      short8_t vbl = *(const short8_t*)&VtL[dt * 16 + fr][kh * 8];
      oacc[dt] = __builtin_amdgcn_mfma_f32_16x16x32_bf16(pah, vbh, oacc[dt], 0, 0, 0);
      oacc[dt] = __builtin_amdgcn_mfma_f32_16x16x32_bf16(pal, vbh, oacc[dt], 0, 0, 0);
      oacc[dt] = __builtin_amdgcn_mfma_f32_16x16x32_bf16(pah, vbl, oacc[dt], 0, 0, 0);
    }
  }

  float li0 = __shfl(lrun, kh * 4 + 0);
  float li1 = __shfl(lrun, kh * 4 + 1);
  float li2 = __shfl(lrun, kh * 4 + 2);
  float li3 = __shfl(lrun, kh * 4 + 3);
  float linv[4] = {1.f / li0, 1.f / li1, 1.f / li2, 1.f / li3};
#pragma unroll
  for (int j = 0; j < 4; ++j) {
    int qrow = qw + kh * 4 + j;
    if (qrow >= T_) continue;
    size_t base = ((size_t)(b * T_ + qrow)) * D_ + hh * DH_;
#pragma unroll
    for (int dt = 0; dt < 4; ++dt)
      o[base + dt * 16 + fr] = oacc[dt][j] * linv[j];
  }
}

// ---------------- h = rms(h + f) * g variants (f = sum of partials)
__global__ __launch_bounds__(256) void rmsadd_kernel(
    float* __restrict__ h, const float* __restrict__ f, const float* __restrict__ g) {
  int row = blockIdx.x;
  int tx = threadIdx.x;
  size_t base = (size_t)row * D_;
  float x[4];
  float ss = 0.f;
#pragma unroll
  for (int i = 0; i < 4; ++i) {
    int d = tx + 256 * i;
    x[i] = h[base + d] + f[base + d];
    ss += x[i] * x[i];
  }
  __shared__ float red[4];
#pragma unroll
  for (int m = 32; m; m >>= 1) ss += __shfl_xor(ss, m);
  if ((tx & 63) == 0) red[tx >> 6] = ss;
  __syncthreads();
  float tot = red[0] + red[1] + red[2] + red[3];
  float r = rsqrtf(tot * (1.f / (float)D_) + 1e-6f);
#pragma unroll
  for (int i = 0; i < 4; ++i) {
    int d = tx + 256 * i;
    h[base + d] = x[i] * r * g[d];
  }
}

__global__ __launch_bounds__(256) void rmsadd2_kernel(
    float* __restrict__ h, const float* __restrict__ f0, const float* __restrict__ f1,
    const float* __restrict__ g) {
  int row = blockIdx.x;
  int tx = threadIdx.x;
  size_t base = (size_t)row * D_;
  float x[4];
  float ss = 0.f;
#pragma unroll
  for (int i = 0; i < 4; ++i) {
    int d = tx + 256 * i;
    x[i] = h[base + d] + (f0[base + d] + f1[base + d]);
    ss += x[i] * x[i];
  }
  __shared__ float red[4];
#pragma unroll
  for (int m = 32; m; m >>= 1) ss += __shfl_xor(ss, m);
  if ((tx & 63) == 0) red[tx >> 6] = ss;
  __syncthreads();
  float tot = red[0] + red[1] + red[2] + red[3];
  float r = rsqrtf(tot * (1.f / (float)D_) + 1e-6f);
#pragma unroll
  for (int i = 0; i < 4; ++i) {
    int d = tx + 256 * i;
    h[base + d] = x[i] * r * g[d];
  }
}

__global__ __launch_bounds__(256) void rmsadd4_kernel(
    float* __restrict__ h, const float* __restrict__ f0, const float* __restrict__ f1,
    const float* __restrict__ f2, const float* __restrict__ f3, const float* __restrict__ g) {
  int row = blockIdx.x;
  int tx = threadIdx.x;
  size_t base = (size_t)row * D_;
  float x[4];
  float ss = 0.f;
#pragma unroll
  for (int i = 0; i < 4; ++i) {
    int d = tx + 256 * i;
    x[i] = h[base + d] + ((f0[base + d] + f1[base + d]) + (f2[base + d] + f3[base + d]));
    ss += x[i] * x[i];
  }
  __shared__ float red[4];
#pragma unroll
  for (int m = 32; m; m >>= 1) ss += __shfl_xor(ss, m);
  if ((tx & 63) == 0) red[tx >> 6] = ss;
  __syncthreads();
  float tot = red[0] + red[1] + red[2] + red[3];
  float r = rsqrtf(tot * (1.f / (float)D_) + 1e-6f);
#pragma unroll
  for (int i = 0; i < 4; ++i) {
    int d = tx + 256 * i;
    h[base + d] = x[i] * r * g[d];
  }
}

// ---------------- a1 = silu(a1) * a3
__global__ __launch_bounds__(256) void swiglu_kernel(
    float* __restrict__ a1, const float* __restrict__ a3, size_t n) {
  size_t idx = (size_t)blockIdx.x * 256 + threadIdx.x;
  if (idx < n) {
    float x = a1[idx];
    float sig = 1.f / (1.f + expf(-x));
    a1[idx] = x * sig * a3[idx];
  }
}

// ---------------- per-row logsumexp + CE partials
__global__ __launch_bounds__(256) void loss_kernel(
    const float* __restrict__ logits, const int* __restrict__ tokens, float* __restrict__ acc) {
  int row = blockIdx.x;
  int tx = threadIdx.x;
  const float* lr = logits + (size_t)row * V_;
  __shared__ float red[4];

  float mx = -INFINITY;
  for (int jv = tx; jv < V_; jv += 256) mx = fmaxf(mx, lr[jv]);
#pragma unroll
  for (int m = 32; m; m >>= 1) mx = fmaxf(mx, __shfl_xor(mx, m));
  if ((tx & 63) == 0) red[tx >> 6] = mx;
  __syncthreads();
  mx = fmaxf(fmaxf(red[0], red[1]), fmaxf(red[2], red[3]));
  __syncthreads();

  float se = 0.f;
  for (int jv = tx; jv < V_; jv += 256) se += expf(lr[jv] - mx);
#pragma unroll
  for (int m = 32; m; m >>= 1) se += __shfl_xor(se, m);
  if ((tx & 63) == 0) red[tx >> 6] = se;
  __syncthreads();
  se = red[0] + red[1] + red[2] + red[3];

  if (tx == 0) {
    float lse = mx + logf(se);
    float lt = lr[tokens[row]];
    atomicAdd(&acc[0], lse - lt);
    atomicAdd(&acc[1], lse * lse);
  }
}

__global__ void zero_acc_kernel(float* acc) {
  if (threadIdx.x < 2) acc[threadIdx.x] = 0.f;
}

__global__ void finalize_kernel(const float* __restrict__ acc, float* __restrict__ out) {
  out[0] = acc[0] * (1.f / (float)BT_) + 1e-4f * acc[1] * (1.f / (float)BT_);
}

static inline dim3 gemm_grid(int M, int N) {
  return dim3((unsigned)((N + 127) / 128), (unsigned)((M + 127) / 128));
}

extern "C" void kernel_launch(void* const* d_in, const int* in_sizes, int n_in,
                              void* d_out, int out_size, void* d_ws, size_t ws_size,
                              hipStream_t stream) {
  const int* i0 = (const int*)d_in[0];
  const int* i1 = (const int*)d_in[1];
  const int* i2 = (const int*)d_in[2];
  const int* i3 = (const int*)d_in[3];
  const int* i4 = (const int*)d_in[4];
  const int* i5 = (const int*)d_in[5];
  const float* temb = (const float*)d_in[6];
  const float* semb = (const float*)d_in[7];
  const float* stok = (const float*)d_in[8];
  const float* wq = (const float*)d_in[9];
  const float* wk = (const float*)d_in[10];
  const float* wv = (const float*)d_in[11];
  const float* wo = (const float*)d_in[12];
  const float* qn = (const float*)d_in[13];
  const float* kn = (const float*)d_in[14];
  const float* n1 = (const float*)d_in[15];
  const float* n2 = (const float*)d_in[16];
  const float* w1 = (const float*)d_in[17];
  const float* w3 = (const float*)d_in[18];
  const float* w2 = (const float*)d_in[19];

  const size_t S  = (size_t)BT_ * D_;     // 2,795,520 floats
  const size_t F  = (size_t)BT_ * DFF_;   // 7,512,960 floats
  float* ws = (float*)d_ws;
  float* h  = ws;
  float* R  = ws + S;                      // union region [2F]
  // attention phase
  float* qb   = R;
  float* kb   = R + S;
  float* vb   = R + 2 * S;
  float* ob   = R + 4 * S;                 // attn output (R+4S..R+5S < R+2F)
  // wo split-K partials: R..4S (qb/kb/vb dead after attn; R+3S unused)
  float* wop0 = R;
  float* wop1 = R + S;
  float* wop2 = R + 2 * S;
  float* wop3 = R + 3 * S;
  // FFN phase
  float* a1   = R;                         // [F]
  float* a3   = R + F;                     // consumed by swiglu
  float* w2p0 = R + F;                     // w2 split-K partials (a3 dead)
  float* w2p1 = R + F + S;
  float* logits = R;
  int*   tokens = (int*)(ws + S + 2 * F);
  float* acc    = ws + S + 2 * F + ((BT_ + 15) & ~1);

  dim3 blk(256);
  embed_kernel<<<BT_, blk, 0, stream>>>(i0, i1, i2, i3, i4, i5, temb, semb, stok, h, tokens);

  for (int l = 0; l < NL_; ++l) {
    const float* wql = wq + (size_t)l * D_ * D_;
    const float* wkl = wk + (size_t)l * D_ * D_;
    const float* wvl = wv + (size_t)l * D_ * D_;
    const float* wol = wo + (size_t)l * D_ * D_;
    const float* w1l = w1 + (size_t)l * D_ * DFF_;
    const float* w3l = w3 + (size_t)l * D_ * DFF_;
    const float* w2l = w2 + (size_t)l * DFF_ * D_;

    gemm_qkv<<<dim3(24, (BT_ + 127) / 128), blk, 0, stream>>>(h, wql, wkl, wvl, qb, kb, vb, BT_, D_);
    qkrope_kernel<<<BT_ * H_, dim3(64), 0, stream>>>(qb, kb, qn + (size_t)l * DH_, kn + (size_t)l * DH_);
    attn_mfma<<<dim3((T_ + 63) / 64, H_, B_), blk, 0, stream>>>(qb, kb, vb, ob);
    // wo: split-K x4 (K=1024 -> 4 chunks of 256)
    gemm_splitk<0><<<dim3(8, (BT_ + 127) / 128, 4), blk, 0, stream>>>(
        ob, wol, wop0, wop1, wop2, wop3, BT_, D_, D_, 256);
    rmsadd4_kernel<<<BT_, blk, 0, stream>>>(h, wop0, wop1, wop2, wop3, n1 + (size_t)l * D_);
    gemm_w13<<<dim3(44, (BT_ + 127) / 128), blk, 0, stream>>>(h, w1l, w3l, a1, a3, BT_, D_);
    {
      size_t n = (size_t)BT_ * DFF_;
      swiglu_kernel<<<(unsigned)((n + 255) / 256), blk, 0, stream>>>(a1, a3, n);
    }
    // w2: split-K x2 (K=2752 -> 2 chunks of 1376)
    gemm_splitk<0><<<dim3(8, (BT_ + 127) / 128, 2), blk, 0, stream>>>(
        a1, w2l, w2p0, w2p1, nullptr, nullptr, BT_, D_, DFF_, 1376);
    rmsadd2_kernel<<<BT_, blk, 0, stream>>>(h, w2p0, w2p1, n2 + (size_t)l * D_);
  }

  gemm_mfma<1><<<gemm_grid(BT_, V_), blk, 0, stream>>>(h, temb, logits, BT_, V_, D_);
  zero_acc_kernel<<<1, 64, 0, stream>>>(acc);
  loss_kernel<<<BT_, blk, 0, stream>>>(logits, tokens, acc);
  finalize_kernel<<<1, 1, 0, stream>>>(acc, (float*)d_out);
}